// Round 7
// baseline (173.854 us; speedup 1.0000x reference)
//
#include <hip/hip_runtime.h>
#include <hip/hip_bf16.h>
#include <math.h>

// ---------------------------------------------------------------------------
// TGCN: z/r/h GCN gates + GRU + readout.
// R1: segment_sum(w * (x@W)[src]) == segment_sum(w * x[src]) @ W
//     -> aggregate raw features ONCE (AX), fold W_g into Wl_g top half.
// R2: gate GEMMs on MFMA (bf16 in, f32 acc); weights pre-fused in d_ws.
// R3: packed bf16 atomics -> device atomic ceiling (~300M req/s) = 85us.
// R4: bucket-LDS agg FAILED (2 blk/CU, latency-bound).
// R5/R6: edge restructure FAILED on random 8B STORES: 800K partial-line
//     write-throughs = 50MB @ 790GB/s = 65us. Atomics sustain 30x the
//     request rate of scattered stores (R3 evidence).
// R7: ELL with 4B slots {w_bf15|src17}, one 64B line per node; slot written
//     via atomicAdd into zeroed ELL (add-to-zero = store, unique rank slot)
//     -> rides the fast atomic path. Aggregate: branch-free 16-slot unroll
//     (empty slot => w=0 contributes 0). Overflow (deg>16) -> pk-bf16 atomics.
// ---------------------------------------------------------------------------

#define PAD 16

typedef __attribute__((ext_vector_type(8))) short bf16x8;   // 8 bf16 = 4 VGPR
typedef __attribute__((ext_vector_type(4))) float f32x4;    // MFMA C/D

static __device__ __forceinline__ short f2bf(float x) {
    union { float f; unsigned u; } v; v.f = x;
    unsigned r = v.u + 0x7fffu + ((v.u >> 16) & 1u);        // RNE
    return (short)(r >> 16);
}
__device__ __forceinline__ float sigmoid_(float x) { return 1.0f / (1.0f + __expf(-x)); }
__device__ __forceinline__ float tanh_(float x)    { return 1.0f - 2.0f / (__expf(2.0f * x) + 1.0f); }

// zero AXb[N*64 bf16], ELL4[N*PAD u32], cnt[N]
__global__ __launch_bounds__(256) void prep_ell_kernel(
    short* __restrict__ AXb, unsigned* __restrict__ ELL4,
    int* __restrict__ cnt, int N)
{
    int gid = blockIdx.x * blockDim.x + threadIdx.x;
    int stride = gridDim.x * blockDim.x;
    const uint4 z = make_uint4(0, 0, 0, 0);
    for (int i = gid; i < N; i += stride) cnt[i] = 0;
    int nAX = N * 8;                       // N*64 shorts = N*8 uint4
    for (int i = gid; i < nAX; i += stride) ((uint4*)AXb)[i] = z;
    int nEL = N * (PAD / 4);               // N*PAD u32 = N*4 uint4
    for (int i = gid; i < nEL; i += stride) ((uint4*)ELL4)[i] = z;
}

// one thread per edge: rank via atomic; slot "store" via atomicAdd into the
// zeroed slot (atomics write through at ~300M req/s; plain scattered stores
// cost a full line each). Overflow -> pk-bf16 atomics into AXb.
__global__ __launch_bounds__(256) void build_ell_kernel(
    const int* __restrict__ ei, const float* __restrict__ ew,
    const float* __restrict__ x, int* __restrict__ cnt,
    unsigned* __restrict__ ELL4, short* __restrict__ AXb, int E)
{
    int i = blockIdx.x * 256 + threadIdx.x;
    if (i < E) {
        int src = ei[i];
        int dst = ei[E + i];
        unsigned u = __float_as_uint(ew[i]);
        // RNE round to bf16, drop sign (edge_weight >= 0)
        unsigned wb = ((u + 0x7fffu + ((u >> 16) & 1u)) >> 16) & 0x7fffu;
        int rank = atomicAdd(&cnt[dst], 1);
        if (rank < PAD) {
            atomicAdd(&ELL4[(size_t)dst * PAD + rank], (wb << 17) | (unsigned)src);
        } else {
            float w = __uint_as_float(u);
#pragma unroll 4
            for (int j = 0; j < 32; j++) {
                float2 xv = *(const float2*)(x + (size_t)src * 64 + j * 2);
                unsigned pk = (unsigned)(unsigned short)f2bf(xv.x * w)
                            | ((unsigned)(unsigned short)f2bf(xv.y * w) << 16);
                short* addr = AXb + (size_t)dst * 64 + j * 2;
                asm volatile("global_atomic_pk_add_bf16 %0, %1, off"
                             :: "v"(addr), "v"(pk) : "memory");
            }
        }
    }
    asm volatile("s_waitcnt vmcnt(0)" ::: "memory");   // drain before endpgm
}

// half-wave per node: read the 64B slot row (4 uniform uint4 = broadcast),
// 16 branch-free gathers (empty slot: w=0 -> contributes 0), f32 regs,
// add overflow residue, store packed bf16.
__global__ __launch_bounds__(512) void aggregate_ell_kernel(
    const float* __restrict__ x, const uint4* __restrict__ ELL4,
    short* __restrict__ AXb, int N)
{
    int hw = (blockIdx.x * 512 + threadIdx.x) >> 5;   // node id
    int lj = threadIdx.x & 31;                        // feature pair
    if (hw >= N) return;
    const uint4* rp = ELL4 + (size_t)hw * (PAD / 4);
    uint4 q0 = rp[0], q1 = rp[1], q2 = rp[2], q3 = rp[3];
    float a0 = 0.f, a1 = 0.f;
#define STEP(s) { unsigned sl = (s);                                          \
        float w = __uint_as_float((sl >> 17) << 16);                          \
        float2 xv = *(const float2*)(x + (size_t)(sl & 0x1FFFFu) * 64 + lj * 2); \
        a0 = fmaf(xv.x, w, a0); a1 = fmaf(xv.y, w, a1); }
    STEP(q0.x) STEP(q0.y) STEP(q0.z) STEP(q0.w)
    STEP(q1.x) STEP(q1.y) STEP(q1.z) STEP(q1.w)
    STEP(q2.x) STEP(q2.y) STEP(q2.z) STEP(q2.w)
    STEP(q3.x) STEP(q3.y) STEP(q3.z) STEP(q3.w)
#undef STEP
    // add overflow residue accumulated in AXb by build_ell
    unsigned prev = *(unsigned*)(AXb + (size_t)hw * 64 + lj * 2);
    a0 += __uint_as_float(prev << 16);
    a1 += __uint_as_float(prev & 0xffff0000u);
    unsigned pk = (unsigned)(unsigned short)f2bf(a0)
                | ((unsigned)(unsigned short)f2bf(a1) << 16);
    *(unsigned*)(AXb + (size_t)hw * 64 + lj * 2) = pk;
}

// ---- fallback path (R3): xb conversion + packed bf16 global atomics --------
__global__ __launch_bounds__(256) void prep_kernel(
    const float* __restrict__ x, short* __restrict__ xb,
    short* __restrict__ AXb, int n8)
{
    int gid = blockIdx.x * blockDim.x + threadIdx.x;
    int stride = gridDim.x * blockDim.x;
    for (int i = gid; i < n8; i += stride) {
        float4 a = ((const float4*)x)[i * 2];
        float4 b = ((const float4*)x)[i * 2 + 1];
        bf16x8 v;
        v[0] = f2bf(a.x); v[1] = f2bf(a.y); v[2] = f2bf(a.z); v[3] = f2bf(a.w);
        v[4] = f2bf(b.x); v[5] = f2bf(b.y); v[6] = f2bf(b.z); v[7] = f2bf(b.w);
        ((bf16x8*)xb)[i] = v;
        bf16x8 z = {0, 0, 0, 0, 0, 0, 0, 0};
        ((bf16x8*)AXb)[i] = z;
    }
}

__global__ __launch_bounds__(256) void scatter_kernel(
    const short* __restrict__ xb, const float* __restrict__ ew,
    const int* __restrict__ ei, short* __restrict__ AXb, int E)
{
    int hw  = (blockIdx.x * 256 + threadIdx.x) >> 5;
    int lj  = threadIdx.x & 31;
    int nhw = (gridDim.x * 256) >> 5;
    for (int e = hw; e < E; e += nhw) {
        int src = ei[e];
        int dst = ei[E + e];
        float w = ew[e];
        unsigned pv = *(const unsigned*)(xb + (size_t)src * 64 + lj * 2);
        float lo = __uint_as_float(pv << 16) * w;
        float hi = __uint_as_float(pv & 0xffff0000u) * w;
        unsigned pk = (unsigned)(unsigned short)f2bf(lo)
                    | ((unsigned)(unsigned short)f2bf(hi) << 16);
        short* addr = AXb + (size_t)dst * 64 + lj * 2;
        asm volatile("global_atomic_pk_add_bf16 %0, %1, off"
                     :: "v"(addr), "v"(pk) : "memory");
    }
    asm volatile("s_waitcnt vmcnt(0)" ::: "memory");
}

// Produces, in d_ws:
//   WT[m][64][64] bf16, n-major (transposed), m = 0..6:
//     0..2 : W_g @ Wl_g_top ; 3..5 : Wl_g_bottom ; 6 : W_out
//   bfv[4][64] f32: fused biases
__global__ __launch_bounds__(256) void fuse_weights_kernel(
    const float* __restrict__ Wz, const float* __restrict__ Wr, const float* __restrict__ Wh,
    const float* __restrict__ bz, const float* __restrict__ br, const float* __restrict__ bh,
    const float* __restrict__ Wlz, const float* __restrict__ Wlr, const float* __restrict__ Wlh,
    const float* __restrict__ blz, const float* __restrict__ blr, const float* __restrict__ blh,
    const float* __restrict__ Wout, const float* __restrict__ bout_,
    short* __restrict__ WT, float* __restrict__ bfv)
{
    int g = blockIdx.x;
    int tid = threadIdx.x;
    if (g == 3) {
        for (int i = tid; i < 4096; i += 256) {
            int k = i >> 6, n = i & 63;
            WT[6 * 4096 + n * 64 + k] = f2bf(Wout[k * 64 + n]);
        }
        if (tid < 64) bfv[192 + tid] = bout_[tid];
        return;
    }
    const float* Win = (g == 0) ? Wz : (g == 1) ? Wr : Wh;
    const float* Wl  = (g == 0) ? Wlz : (g == 1) ? Wlr : Wlh;
    const float* b   = (g == 0) ? bz : (g == 1) ? br : bh;
    const float* bl  = (g == 0) ? blz : (g == 1) ? blr : blh;

    __shared__ float wl_s[64][65];
    for (int i = tid; i < 4096; i += 256) wl_s[i >> 6][i & 63] = Wl[i];
    __syncthreads();

    int k = tid >> 2;
    int j0 = (tid & 3) << 4;
    float acc[16];
#pragma unroll
    for (int jj = 0; jj < 16; jj++) acc[jj] = 0.f;
    for (int t = 0; t < 64; t++) {
        float a = Win[k * 64 + t];
#pragma unroll
        for (int jj = 0; jj < 16; jj++) acc[jj] = fmaf(a, wl_s[t][j0 + jj], acc[jj]);
    }
#pragma unroll
    for (int jj = 0; jj < 16; jj++) WT[g * 4096 + (j0 + jj) * 64 + k] = f2bf(acc[jj]);

    for (int i = tid; i < 4096; i += 256) {
        int kk = i >> 6, n = i & 63;
        WT[(3 + g) * 4096 + n * 64 + kk] = f2bf(Wl[(64 + kk) * 64 + n]);
    }
    if (tid < 64) {
        float a2 = bl[tid];
        for (int t = 0; t < 64; t++) a2 = fmaf(b[t], wl_s[t][tid], a2);
        bfv[g * 64 + tid] = a2;
    }
}

// Fused GRU gates + readout via MFMA. 64-node tile, 4 waves.
__global__ __launch_bounds__(256, 3) void gates_kernel(
    const short* __restrict__ AXb, const float* __restrict__ hid,
    const short* __restrict__ WT, const float* __restrict__ bfv,
    float* __restrict__ outY, float* __restrict__ outH, int nNodes)
{
    __shared__ short axs[64][72];
    __shared__ short hs [64][72];
    __shared__ short rsb[64][72];
    __shared__ float hf [64][68];

    const int tid  = threadIdx.x;
    const int w    = tid >> 6;
    const int lane = tid & 63;
    const int lr   = lane & 15;
    const int lg   = lane >> 4;
    const int col  = w * 16 + lr;
    const int n0   = blockIdx.x * 64;

    {
        int row = tid >> 2;
        int c0  = (tid & 3) << 4;
        int n   = n0 + row;
        bool valid = n < nNodes;
        const float4 z4 = make_float4(0.f, 0.f, 0.f, 0.f);
        const bf16x8 zb = {0, 0, 0, 0, 0, 0, 0, 0};
        bf16x8 a0 = valid ? *(const bf16x8*)(AXb + (size_t)n * 64 + c0)     : zb;
        bf16x8 a1 = valid ? *(const bf16x8*)(AXb + (size_t)n * 64 + c0 + 8) : zb;
        *(bf16x8*)(&axs[row][c0])     = a0;
        *(bf16x8*)(&axs[row][c0 + 8]) = a1;
#pragma unroll
        for (int q = 0; q < 4; q++) {
            float4 vh = valid ? *(const float4*)(hid + (size_t)n * 64 + c0 + q * 4) : z4;
            int c = c0 + q * 4;
            hs[row][c + 0] = f2bf(vh.x); hs[row][c + 1] = f2bf(vh.y);
            hs[row][c + 2] = f2bf(vh.z); hs[row][c + 3] = f2bf(vh.w);
            hf[row][c + 0] = vh.x; hf[row][c + 1] = vh.y;
            hf[row][c + 2] = vh.z; hf[row][c + 3] = vh.w;
        }
    }

    bf16x8 wf[7][2];
#pragma unroll
    for (int m = 0; m < 7; m++)
#pragma unroll
        for (int kb = 0; kb < 2; kb++)
            wf[m][kb] = *(const bf16x8*)(WT + m * 4096 + col * 64 + kb * 32 + lg * 8);
    const float bz_ = bfv[col], br_ = bfv[64 + col], bh_ = bfv[128 + col], bo_ = bfv[192 + col];

    __syncthreads();

    const f32x4 zero4 = {0.f, 0.f, 0.f, 0.f};
    f32x4 accz[4], accr[4], acch[4];
#pragma unroll
    for (int rt = 0; rt < 4; rt++) { accz[rt] = zero4; accr[rt] = zero4; acch[rt] = zero4; }

#pragma unroll
    for (int rt = 0; rt < 4; rt++) {
        int arow = rt * 16 + lr;
#pragma unroll
        for (int kb = 0; kb < 2; kb++) {
            bf16x8 aa = *(const bf16x8*)(&axs[arow][kb * 32 + lg * 8]);
            bf16x8 ah = *(const bf16x8*)(&hs [arow][kb * 32 + lg * 8]);
            accz[rt] = __builtin_amdgcn_mfma_f32_16x16x32_bf16(aa, wf[0][kb], accz[rt], 0, 0, 0);
            accr[rt] = __builtin_amdgcn_mfma_f32_16x16x32_bf16(aa, wf[1][kb], accr[rt], 0, 0, 0);
            acch[rt] = __builtin_amdgcn_mfma_f32_16x16x32_bf16(aa, wf[2][kb], acch[rt], 0, 0, 0);
            accz[rt] = __builtin_amdgcn_mfma_f32_16x16x32_bf16(ah, wf[3][kb], accz[rt], 0, 0, 0);
            accr[rt] = __builtin_amdgcn_mfma_f32_16x16x32_bf16(ah, wf[4][kb], accr[rt], 0, 0, 0);
        }
    }

    float zf[16];
#pragma unroll
    for (int rt = 0; rt < 4; rt++) {
#pragma unroll
        for (int i = 0; i < 4; i++) {
            int row = rt * 16 + lg * 4 + i;
            float z = sigmoid_(accz[rt][i] + bz_);
            float r = sigmoid_(accr[rt][i] + br_);
            zf[rt * 4 + i] = z;
            rsb[row][col] = f2bf(r * hf[row][col]);
        }
    }
    __syncthreads();

#pragma unroll
    for (int rt = 0; rt < 4; rt++) {
        int arow = rt * 16 + lr;
#pragma unroll
        for (int kb = 0; kb < 2; kb++) {
            bf16x8 ar = *(const bf16x8*)(&rsb[arow][kb * 32 + lg * 8]);
            acch[rt] = __builtin_amdgcn_mfma_f32_16x16x32_bf16(ar, wf[5][kb], acch[rt], 0, 0, 0);
        }
    }
#pragma unroll
    for (int rt = 0; rt < 4; rt++) {
#pragma unroll
        for (int i = 0; i < 4; i++) {
            int row = rt * 16 + lg * 4 + i;
            float ht = tanh_(acch[rt][i] + bh_);
            float z  = zf[rt * 4 + i];
            float hv = z * hf[row][col] + (1.f - z) * ht;
            int n = n0 + row;
            if (n < nNodes) outH[(size_t)n * 64 + col] = hv;
            axs[row][col] = f2bf(fmaxf(hv, 0.f));
        }
    }
    __syncthreads();

    f32x4 accy[4];
#pragma unroll
    for (int rt = 0; rt < 4; rt++) accy[rt] = zero4;
#pragma unroll
    for (int rt = 0; rt < 4; rt++) {
        int arow = rt * 16 + lr;
#pragma unroll
        for (int kb = 0; kb < 2; kb++) {
            bf16x8 aa = *(const bf16x8*)(&axs[arow][kb * 32 + lg * 8]);
            accy[rt] = __builtin_amdgcn_mfma_f32_16x16x32_bf16(aa, wf[6][kb], accy[rt], 0, 0, 0);
        }
    }
#pragma unroll
    for (int rt = 0; rt < 4; rt++) {
#pragma unroll
        for (int i = 0; i < 4; i++) {
            int row = rt * 16 + lg * 4 + i;
            int n = n0 + row;
            if (n < nNodes) outY[(size_t)n * 64 + col] = accy[rt][i] + bo_;
        }
    }
}

extern "C" void kernel_launch(void* const* d_in, const int* in_sizes, int n_in,
                              void* d_out, int out_size, void* d_ws, size_t ws_size,
                              hipStream_t stream)
{
    const float* node_feat = (const float*)d_in[0];
    const float* edge_w    = (const float*)d_in[1];
    const float* hidden    = (const float*)d_in[2];
    const float* W_z  = (const float*)d_in[3];
    const float* b_z  = (const float*)d_in[4];
    const float* W_r  = (const float*)d_in[5];
    const float* b_r  = (const float*)d_in[6];
    const float* W_h  = (const float*)d_in[7];
    const float* b_h  = (const float*)d_in[8];
    const float* Wl_z = (const float*)d_in[9];
    const float* bl_z = (const float*)d_in[10];
    const float* Wl_r = (const float*)d_in[11];
    const float* bl_r = (const float*)d_in[12];
    const float* Wl_h = (const float*)d_in[13];
    const float* bl_h = (const float*)d_in[14];
    const float* W_out = (const float*)d_in[15];
    const float* b_out = (const float*)d_in[16];
    const int*   edge_index = (const int*)d_in[17];

    const int N = in_sizes[0] / 64;
    const int E = in_sizes[1];

    char* ws = (char*)d_ws;
    size_t off = 0;
    short* AXb = (short*)(ws + off); off += (size_t)N * 64 * 2;
    // union: ELL4 (N*PAD*4 = N*64B) on ELL path, xb (N*128B) on fallback
    char*  uni = ws + off;           off += (size_t)N * 128;
    short* WT  = (short*)(ws + off); off += 7 * 4096 * 2;
    float* bfv = (float*)(ws + off); off += 4 * 64 * 4;
    int*   cnt = (int*)(ws + off);   off += (size_t)N * 4;

    const bool useELL = (ws_size >= off) && (N <= (1 << 17));  // src fits 17 bits

    float* outY = (float*)d_out;                 // [N,64]
    float* outH = outY + (size_t)N * 64;         // [N,64]

    fuse_weights_kernel<<<4, 256, 0, stream>>>(W_z, W_r, W_h, b_z, b_r, b_h,
                                               Wl_z, Wl_r, Wl_h, bl_z, bl_r, bl_h,
                                               W_out, b_out, WT, bfv);
    if (useELL) {
        unsigned* ELL4 = (unsigned*)uni;
        prep_ell_kernel<<<2048, 256, 0, stream>>>(AXb, ELL4, cnt, N);
        build_ell_kernel<<<(E + 255) / 256, 256, 0, stream>>>(
            edge_index, edge_w, node_feat, cnt, ELL4, AXb, E);
        aggregate_ell_kernel<<<(N * 32 + 511) / 512, 512, 0, stream>>>(
            node_feat, (const uint4*)ELL4, AXb, N);
    } else {
        short* xb = (short*)uni;
        prep_kernel<<<2048, 256, 0, stream>>>(node_feat, xb, AXb, N * 8);
        scatter_kernel<<<2048, 256, 0, stream>>>(xb, edge_w, edge_index, AXb, E);
    }

    int nblk = (N + 63) / 64;
    gates_kernel<<<nblk, 256, 0, stream>>>(AXb, hidden, WT, bfv, outY, outH, N);
}

// Round 8
// 172.943 us; speedup vs baseline: 1.0053x; 1.0053x over previous
//
#include <hip/hip_runtime.h>
#include <hip/hip_bf16.h>
#include <math.h>

// ---------------------------------------------------------------------------
// TGCN: z/r/h GCN gates + GRU + readout.
// R1: segment_sum(w * (x@W)[src]) == segment_sum(w * x[src]) @ W
//     -> aggregate raw features ONCE (AX), fold W_g into Wl_g top half.
// R2: gate GEMMs on MFMA (bf16 in, f32 acc); weights pre-fused in d_ws.
// R3: coalesced pk-bf16 atomics: 25.6M dword-reqs @ 125/cy ceiling = 85us.
// R4-R7: ALL edge-restructure attempts lose: scattered small writes (store
//     or atomic) cost one 64B line each (~800K lines = 65-84us). Law:
//     coalesce-or-die; below 85us only via FEWER/WIDER atomic requests.
// R8: 4 features per 64-bit atomic: biased 16-bit fixed point
//     slot = RNE(w*x*128) + 2^14; u64 add; cross-slot carries recovered
//     exactly in decode given node degree k (hist); k>24 nodes (never, for
//     Poisson-8) spill to f32 atomics in zeroed outH. 12.8M u64 reqs.
//     + gates LDS diet: drop f32 hid tile -> 27.6KB LDS, 4 blk/CU.
// ---------------------------------------------------------------------------

#define SPILL  24
#define QBIAS  16384

typedef __attribute__((ext_vector_type(8))) short bf16x8;   // 8 bf16 = 4 VGPR
typedef __attribute__((ext_vector_type(4))) float f32x4;    // MFMA C/D

static __device__ __forceinline__ short f2bf(float x) {
    union { float f; unsigned u; } v; v.f = x;
    unsigned r = v.u + 0x7fffu + ((v.u >> 16) & 1u);        // RNE
    return (short)(r >> 16);
}
static __device__ __forceinline__ float bf2f(short s) {
    return __uint_as_float((unsigned)(unsigned short)s << 16);
}
__device__ __forceinline__ float sigmoid_(float x) { return 1.0f / (1.0f + __expf(-x)); }
__device__ __forceinline__ float tanh_(float x)    { return 1.0f - 2.0f / (__expf(2.0f * x) + 1.0f); }

// zero AXq[N*16 u64], spill[N*64 f32] (= outH region), cnt[N]
__global__ __launch_bounds__(256) void prep_q_kernel(
    unsigned long long* __restrict__ AXq, float* __restrict__ spill,
    int* __restrict__ cnt, int N)
{
    int gid = blockIdx.x * blockDim.x + threadIdx.x;
    int stride = gridDim.x * blockDim.x;
    const uint4 z = make_uint4(0, 0, 0, 0);
    for (int i = gid; i < N; i += stride) cnt[i] = 0;
    int nq = N * 8;                        // N*16 u64 = N*8 uint4
    for (int i = gid; i < nq; i += stride) ((uint4*)AXq)[i] = z;
    int ns = N * 16;                       // N*64 f32 = N*16 uint4
    for (int i = gid; i < ns; i += stride) ((uint4*)spill)[i] = z;
}

// degree histogram (needed for carry recovery + spill routing)
__global__ __launch_bounds__(256) void hist_kernel(
    const int* __restrict__ ei, int* __restrict__ cnt, int E)
{
    int gid = blockIdx.x * blockDim.x + threadIdx.x;
    int stride = gridDim.x * blockDim.x;
    for (int i = gid; i < E; i += stride)
        atomicAdd(&cnt[ei[E + i]], 1);
}

// quarter-wave (16 lanes) per edge; lane = one u64 word = 4 features.
// 16 lanes -> 128B contiguous atomic block per edge (coalesced lines).
__global__ __launch_bounds__(256) void scatter_q_kernel(
    const int* __restrict__ ei, const float* __restrict__ ew,
    const float* __restrict__ x, const int* __restrict__ cnt,
    unsigned long long* __restrict__ AXq, float* __restrict__ spill, int E)
{
    int e = (blockIdx.x * 256 + threadIdx.x) >> 4;   // edge id
    int l = threadIdx.x & 15;                        // word id (4 features)
    if (e >= E) return;
    int src = ei[e];
    int dst = ei[E + e];
    float w = ew[e];
    float4 xv = *(const float4*)(x + (size_t)src * 64 + l * 4);
    if (cnt[dst] <= SPILL) {
        int q0 = (int)rintf(xv.x * w * 128.0f) + QBIAS;
        int q1 = (int)rintf(xv.y * w * 128.0f) + QBIAS;
        int q2 = (int)rintf(xv.z * w * 128.0f) + QBIAS;
        int q3 = (int)rintf(xv.w * w * 128.0f) + QBIAS;
        unsigned lo = (unsigned)q0 | ((unsigned)q1 << 16);
        unsigned hi = (unsigned)q2 | ((unsigned)q3 << 16);
        unsigned long long a = (unsigned long long)lo
                             | ((unsigned long long)hi << 32);
        atomicAdd(AXq + (size_t)dst * 16 + l, a);
    } else {                                          // ~never taken
        float* sp = spill + (size_t)dst * 64 + l * 4;
        atomicAdd(sp + 0, xv.x * w);
        atomicAdd(sp + 1, xv.y * w);
        atomicAdd(sp + 2, xv.z * w);
        atomicAdd(sp + 3, xv.w * w);
    }
}

// Produces, in d_ws:
//   WT[m][64][64] bf16, n-major (transposed), m = 0..6:
//     0..2 : W_g @ Wl_g_top ; 3..5 : Wl_g_bottom ; 6 : W_out
//   bfv[4][64] f32: fused biases
__global__ __launch_bounds__(256) void fuse_weights_kernel(
    const float* __restrict__ Wz, const float* __restrict__ Wr, const float* __restrict__ Wh,
    const float* __restrict__ bz, const float* __restrict__ br, const float* __restrict__ bh,
    const float* __restrict__ Wlz, const float* __restrict__ Wlr, const float* __restrict__ Wlh,
    const float* __restrict__ blz, const float* __restrict__ blr, const float* __restrict__ blh,
    const float* __restrict__ Wout, const float* __restrict__ bout_,
    short* __restrict__ WT, float* __restrict__ bfv)
{
    int g = blockIdx.x;
    int tid = threadIdx.x;
    if (g == 3) {
        for (int i = tid; i < 4096; i += 256) {
            int k = i >> 6, n = i & 63;
            WT[6 * 4096 + n * 64 + k] = f2bf(Wout[k * 64 + n]);
        }
        if (tid < 64) bfv[192 + tid] = bout_[tid];
        return;
    }
    const float* Win = (g == 0) ? Wz : (g == 1) ? Wr : Wh;
    const float* Wl  = (g == 0) ? Wlz : (g == 1) ? Wlr : Wlh;
    const float* b   = (g == 0) ? bz : (g == 1) ? br : bh;
    const float* bl  = (g == 0) ? blz : (g == 1) ? blr : blh;

    __shared__ float wl_s[64][65];
    for (int i = tid; i < 4096; i += 256) wl_s[i >> 6][i & 63] = Wl[i];
    __syncthreads();

    int k = tid >> 2;
    int j0 = (tid & 3) << 4;
    float acc[16];
#pragma unroll
    for (int jj = 0; jj < 16; jj++) acc[jj] = 0.f;
    for (int t = 0; t < 64; t++) {
        float a = Win[k * 64 + t];
#pragma unroll
        for (int jj = 0; jj < 16; jj++) acc[jj] = fmaf(a, wl_s[t][j0 + jj], acc[jj]);
    }
#pragma unroll
    for (int jj = 0; jj < 16; jj++) WT[g * 4096 + (j0 + jj) * 64 + k] = f2bf(acc[jj]);

    for (int i = tid; i < 4096; i += 256) {
        int kk = i >> 6, n = i & 63;
        WT[(3 + g) * 4096 + n * 64 + kk] = f2bf(Wl[(64 + kk) * 64 + n]);
    }
    if (tid < 64) {
        float a2 = bl[tid];
        for (int t = 0; t < 64; t++) a2 = fmaf(b[t], wl_s[t][tid], a2);
        bfv[g * 64 + tid] = a2;
    }
}

// Fused GRU gates + readout via MFMA. 64-node tile, 4 waves, 27.6KB LDS.
// AX staged by decoding the fixed-point u64 accumulator (carry recovery).
__global__ __launch_bounds__(256) void gates_kernel(
    const unsigned long long* __restrict__ AXq, const int* __restrict__ cnt,
    const float* __restrict__ spill, const float* __restrict__ hid,
    const short* __restrict__ WT, const float* __restrict__ bfv,
    float* __restrict__ outY, float* __restrict__ outH, int nNodes)
{
    __shared__ short axs[64][72];   // AX tile bf16 (reused for relu(h))
    __shared__ short hs [64][72];   // hid tile bf16
    __shared__ short rsb[64][72];   // r * hid bf16

    const int tid  = threadIdx.x;
    const int w    = tid >> 6;
    const int lane = tid & 63;
    const int lr   = lane & 15;
    const int lg   = lane >> 4;
    const int col  = w * 16 + lr;
    const int n0   = blockIdx.x * 64;

    // ---- stage hid (bf16) and decode AX
    {
        int row = tid >> 2;
        int c0  = (tid & 3) << 4;
        int n   = n0 + row;
        bool valid = n < nNodes;
        const float4 z4 = make_float4(0.f, 0.f, 0.f, 0.f);
#pragma unroll
        for (int q = 0; q < 4; q++) {
            float4 vh = valid ? *(const float4*)(hid + (size_t)n * 64 + c0 + q * 4) : z4;
            int c = c0 + q * 4;
            hs[row][c + 0] = f2bf(vh.x); hs[row][c + 1] = f2bf(vh.y);
            hs[row][c + 2] = f2bf(vh.z); hs[row][c + 3] = f2bf(vh.w);
        }
        int k = valid ? cnt[n] : 0;
        bool sp = valid && (k > SPILL);
        const unsigned long long* qp = AXq + (size_t)n * 16 + (c0 >> 2);
#pragma unroll
        for (int m = 0; m < 4; m++) {
            unsigned long long W = valid ? qp[m] : 0ull;
            int c = 0;
#pragma unroll
            for (int s = 0; s < 4; s++) {
                int t = (int)((unsigned)(W >> (16 * s)) & 0xFFFFu);
                int D = k * QBIAS + c - t;
                int ch = (D + 32768) >> 16;
                int Q = t + (ch << 16) - k * QBIAS - c;
                float f = (float)Q * (1.0f / 128.0f);
                if (sp) f += spill[(size_t)n * 64 + c0 + m * 4 + s];
                axs[row][c0 + m * 4 + s] = f2bf(f);
                c = ch;
            }
        }
    }

    // ---- B-operand fragments for all 7 matrices (56 VGPR)
    bf16x8 wf[7][2];
#pragma unroll
    for (int m = 0; m < 7; m++)
#pragma unroll
        for (int kb = 0; kb < 2; kb++)
            wf[m][kb] = *(const bf16x8*)(WT + m * 4096 + col * 64 + kb * 32 + lg * 8);
    const float bz_ = bfv[col], br_ = bfv[64 + col], bh_ = bfv[128 + col], bo_ = bfv[192 + col];

    __syncthreads();

    const f32x4 zero4 = {0.f, 0.f, 0.f, 0.f};
    f32x4 accz[4], accr[4], acch[4];
#pragma unroll
    for (int rt = 0; rt < 4; rt++) { accz[rt] = zero4; accr[rt] = zero4; acch[rt] = zero4; }

    // ---- phase A: AX-part of z,r,h and hid-part of z,r
#pragma unroll
    for (int rt = 0; rt < 4; rt++) {
        int arow = rt * 16 + lr;
#pragma unroll
        for (int kb = 0; kb < 2; kb++) {
            bf16x8 aa = *(const bf16x8*)(&axs[arow][kb * 32 + lg * 8]);
            bf16x8 ah = *(const bf16x8*)(&hs [arow][kb * 32 + lg * 8]);
            accz[rt] = __builtin_amdgcn_mfma_f32_16x16x32_bf16(aa, wf[0][kb], accz[rt], 0, 0, 0);
            accr[rt] = __builtin_amdgcn_mfma_f32_16x16x32_bf16(aa, wf[1][kb], accr[rt], 0, 0, 0);
            acch[rt] = __builtin_amdgcn_mfma_f32_16x16x32_bf16(aa, wf[2][kb], acch[rt], 0, 0, 0);
            accz[rt] = __builtin_amdgcn_mfma_f32_16x16x32_bf16(ah, wf[3][kb], accz[rt], 0, 0, 0);
            accr[rt] = __builtin_amdgcn_mfma_f32_16x16x32_bf16(ah, wf[4][kb], accr[rt], 0, 0, 0);
        }
    }

    // ---- z, r; rsb <- bf16(r * hid)
    float zf[16];
#pragma unroll
    for (int rt = 0; rt < 4; rt++) {
#pragma unroll
        for (int i = 0; i < 4; i++) {
            int row = rt * 16 + lg * 4 + i;
            float z = sigmoid_(accz[rt][i] + bz_);
            float r = sigmoid_(accr[rt][i] + br_);
            zf[rt * 4 + i] = z;
            rsb[row][col] = f2bf(r * bf2f(hs[row][col]));
        }
    }
    __syncthreads();

    // ---- phase B: h_tilde += (r*hid) @ Wlh_bot ; h ; relu(h) -> axs
#pragma unroll
    for (int rt = 0; rt < 4; rt++) {
        int arow = rt * 16 + lr;
#pragma unroll
        for (int kb = 0; kb < 2; kb++) {
            bf16x8 ar = *(const bf16x8*)(&rsb[arow][kb * 32 + lg * 8]);
            acch[rt] = __builtin_amdgcn_mfma_f32_16x16x32_bf16(ar, wf[5][kb], acch[rt], 0, 0, 0);
        }
    }
#pragma unroll
    for (int rt = 0; rt < 4; rt++) {
#pragma unroll
        for (int i = 0; i < 4; i++) {
            int row = rt * 16 + lg * 4 + i;
            float ht = tanh_(acch[rt][i] + bh_);
            float z  = zf[rt * 4 + i];
            float hv = z * bf2f(hs[row][col]) + (1.f - z) * ht;
            int n = n0 + row;
            if (n < nNodes) outH[(size_t)n * 64 + col] = hv;
            axs[row][col] = f2bf(fmaxf(hv, 0.f));
        }
    }
    __syncthreads();

    // ---- phase C: y = relu(h) @ W_out + b_out
    f32x4 accy[4];
#pragma unroll
    for (int rt = 0; rt < 4; rt++) accy[rt] = zero4;
#pragma unroll
    for (int rt = 0; rt < 4; rt++) {
        int arow = rt * 16 + lr;
#pragma unroll
        for (int kb = 0; kb < 2; kb++) {
            bf16x8 aa = *(const bf16x8*)(&axs[arow][kb * 32 + lg * 8]);
            accy[rt] = __builtin_amdgcn_mfma_f32_16x16x32_bf16(aa, wf[6][kb], accy[rt], 0, 0, 0);
        }
    }
#pragma unroll
    for (int rt = 0; rt < 4; rt++) {
#pragma unroll
        for (int i = 0; i < 4; i++) {
            int row = rt * 16 + lg * 4 + i;
            int n = n0 + row;
            if (n < nNodes) outY[(size_t)n * 64 + col] = accy[rt][i] + bo_;
        }
    }
}

extern "C" void kernel_launch(void* const* d_in, const int* in_sizes, int n_in,
                              void* d_out, int out_size, void* d_ws, size_t ws_size,
                              hipStream_t stream)
{
    const float* node_feat = (const float*)d_in[0];
    const float* edge_w    = (const float*)d_in[1];
    const float* hidden    = (const float*)d_in[2];
    const float* W_z  = (const float*)d_in[3];
    const float* b_z  = (const float*)d_in[4];
    const float* W_r  = (const float*)d_in[5];
    const float* b_r  = (const float*)d_in[6];
    const float* W_h  = (const float*)d_in[7];
    const float* b_h  = (const float*)d_in[8];
    const float* Wl_z = (const float*)d_in[9];
    const float* bl_z = (const float*)d_in[10];
    const float* Wl_r = (const float*)d_in[11];
    const float* bl_r = (const float*)d_in[12];
    const float* Wl_h = (const float*)d_in[13];
    const float* bl_h = (const float*)d_in[14];
    const float* W_out = (const float*)d_in[15];
    const float* b_out = (const float*)d_in[16];
    const int*   edge_index = (const int*)d_in[17];

    const int N = in_sizes[0] / 64;
    const int E = in_sizes[1];

    char* ws = (char*)d_ws;
    size_t off = 0;
    unsigned long long* AXq = (unsigned long long*)(ws + off); off += (size_t)N * 16 * 8;
    short* WT  = (short*)(ws + off); off += 7 * 4096 * 2;
    float* bfv = (float*)(ws + off); off += 4 * 64 * 4;
    int*   cnt = (int*)(ws + off);   off += (size_t)N * 4;

    float* outY  = (float*)d_out;                // [N,64]
    float* outH  = outY + (size_t)N * 64;        // [N,64] (also spill target)
    float* spill = outH;

    prep_q_kernel<<<2048, 256, 0, stream>>>(AXq, spill, cnt, N);
    hist_kernel<<<1024, 256, 0, stream>>>(edge_index, cnt, E);
    fuse_weights_kernel<<<4, 256, 0, stream>>>(W_z, W_r, W_h, b_z, b_r, b_h,
                                               Wl_z, Wl_r, Wl_h, bl_z, bl_r, bl_h,
                                               W_out, b_out, WT, bfv);
    scatter_q_kernel<<<(E * 16 + 255) / 256, 256, 0, stream>>>(
        edge_index, edge_w, node_feat, cnt, AXq, spill, E);

    int nblk = (N + 63) / 64;
    gates_kernel<<<nblk, 256, 0, stream>>>(AXq, cnt, spill, hidden,
                                           WT, bfv, outY, outH, N);
}

// Round 9
// 152.387 us; speedup vs baseline: 1.1409x; 1.1349x over previous
//
#include <hip/hip_runtime.h>
#include <hip/hip_bf16.h>
#include <math.h>

// ---------------------------------------------------------------------------
// TGCN: z/r/h GCN gates + GRU + readout.
// R1: segment_sum(w * (x@W)[src]) == segment_sum(w * x[src]) @ W
//     -> aggregate raw features ONCE (AX), fold W_g into Wl_g top half.
// R2: gate GEMMs on MFMA (bf16 in, f32 acc); weights pre-fused in d_ws.
// R3-R8 scatter lessons (measured):
//   - atomic path is PAYLOAD-BYTE bound: ~102MB write-through @ ~1.3TB/s
//     => ~75-85us floor for 64 bf16 features/edge. Request count secondary.
//   - scattered sub-line stores/atomics cost a full 64B line each (R5/R6/R7)
//     => any edge-restructuring pass >= 65us. hist_kernel alone ~60-65us.
//   - gates: 69KB-LDS version ~50us; 27.6KB slim version ~15-20us.
// R9: consolidation. No hist, no decode, no spill, no xb copy. 4 kernels:
//     zero AXb -> fuse weights -> direct-mapped pk-bf16 scatter (f32 gather)
//     -> slim MFMA gates. Removes ~55us of hidden cost vs R8.
// ---------------------------------------------------------------------------

typedef __attribute__((ext_vector_type(8))) short bf16x8;   // 8 bf16 = 4 VGPR
typedef __attribute__((ext_vector_type(4))) float f32x4;    // MFMA C/D

static __device__ __forceinline__ short f2bf(float x) {
    union { float f; unsigned u; } v; v.f = x;
    unsigned r = v.u + 0x7fffu + ((v.u >> 16) & 1u);        // RNE
    return (short)(r >> 16);
}
static __device__ __forceinline__ float bf2f(short s) {
    return __uint_as_float((unsigned)(unsigned short)s << 16);
}
__device__ __forceinline__ float sigmoid_(float x) { return 1.0f / (1.0f + __expf(-x)); }
__device__ __forceinline__ float tanh_(float x)    { return 1.0f - 2.0f / (__expf(2.0f * x) + 1.0f); }

// zero AXb[N*64 bf16]
__global__ __launch_bounds__(256) void prep_zero_kernel(
    short* __restrict__ AXb, int n16)
{
    int i = blockIdx.x * 256 + threadIdx.x;
    const uint4 z = make_uint4(0, 0, 0, 0);
    if (i < n16) ((uint4*)AXb)[i] = z;
}

// Produces, in d_ws:
//   WT[m][64][64] bf16, n-major (transposed), m = 0..6:
//     0..2 : W_g @ Wl_g_top ; 3..5 : Wl_g_bottom ; 6 : W_out
//   bfv[4][64] f32: fused biases
__global__ __launch_bounds__(256) void fuse_weights_kernel(
    const float* __restrict__ Wz, const float* __restrict__ Wr, const float* __restrict__ Wh,
    const float* __restrict__ bz, const float* __restrict__ br, const float* __restrict__ bh,
    const float* __restrict__ Wlz, const float* __restrict__ Wlr, const float* __restrict__ Wlh,
    const float* __restrict__ blz, const float* __restrict__ blr, const float* __restrict__ blh,
    const float* __restrict__ Wout, const float* __restrict__ bout_,
    short* __restrict__ WT, float* __restrict__ bfv)
{
    int g = blockIdx.x;
    int tid = threadIdx.x;
    if (g == 3) {
        for (int i = tid; i < 4096; i += 256) {
            int k = i >> 6, n = i & 63;
            WT[6 * 4096 + n * 64 + k] = f2bf(Wout[k * 64 + n]);
        }
        if (tid < 64) bfv[192 + tid] = bout_[tid];
        return;
    }
    const float* Win = (g == 0) ? Wz : (g == 1) ? Wr : Wh;
    const float* Wl  = (g == 0) ? Wlz : (g == 1) ? Wlr : Wlh;
    const float* b   = (g == 0) ? bz : (g == 1) ? br : bh;
    const float* bl  = (g == 0) ? blz : (g == 1) ? blr : blh;

    __shared__ float wl_s[64][65];
    for (int i = tid; i < 4096; i += 256) wl_s[i >> 6][i & 63] = Wl[i];
    __syncthreads();

    int k = tid >> 2;
    int j0 = (tid & 3) << 4;
    float acc[16];
#pragma unroll
    for (int jj = 0; jj < 16; jj++) acc[jj] = 0.f;
    for (int t = 0; t < 64; t++) {
        float a = Win[k * 64 + t];
#pragma unroll
        for (int jj = 0; jj < 16; jj++) acc[jj] = fmaf(a, wl_s[t][j0 + jj], acc[jj]);
    }
#pragma unroll
    for (int jj = 0; jj < 16; jj++) WT[g * 4096 + (j0 + jj) * 64 + k] = f2bf(acc[jj]);

    for (int i = tid; i < 4096; i += 256) {        // bottom half of Wl, transposed
        int kk = i >> 6, n = i & 63;
        WT[(3 + g) * 4096 + n * 64 + kk] = f2bf(Wl[(64 + kk) * 64 + n]);
    }
    if (tid < 64) {
        float a2 = bl[tid];
        for (int t = 0; t < 64; t++) a2 = fmaf(b[t], wl_s[t][tid], a2);
        bfv[g * 64 + tid] = a2;
    }
}

// AXb[dst] += bf16(w * x[src]) — one half-wave (32 lanes) per edge, direct
// mapped (max MLP). f32 gather (L2/L3-cached), packed bf16 atomic per dword.
__global__ __launch_bounds__(256) void scatter_kernel(
    const float* __restrict__ x, const float* __restrict__ ew,
    const int* __restrict__ ei, short* __restrict__ AXb, int E)
{
    int e  = (blockIdx.x * 256 + threadIdx.x) >> 5;   // edge id
    int lj = threadIdx.x & 31;                        // feature pair
    if (e < E) {
        int src = ei[e];
        int dst = ei[E + e];
        float w = ew[e];
        float2 xv = *(const float2*)(x + (size_t)src * 64 + lj * 2);
        unsigned pk = (unsigned)(unsigned short)f2bf(xv.x * w)
                    | ((unsigned)(unsigned short)f2bf(xv.y * w) << 16);
        short* addr = AXb + (size_t)dst * 64 + lj * 2;
        asm volatile("global_atomic_pk_add_bf16 %0, %1, off"
                     :: "v"(addr), "v"(pk) : "memory");
    }
    asm volatile("s_waitcnt vmcnt(0)" ::: "memory");   // drain before endpgm
}

// Fused GRU gates + readout via MFMA. 64-node tile, 4 waves, 27.6KB LDS.
__global__ __launch_bounds__(256) void gates_kernel(
    const short* __restrict__ AXb, const float* __restrict__ hid,
    const short* __restrict__ WT, const float* __restrict__ bfv,
    float* __restrict__ outY, float* __restrict__ outH, int nNodes)
{
    __shared__ short axs[64][72];   // AX tile bf16 (reused for relu(h))
    __shared__ short hs [64][72];   // hid tile bf16
    __shared__ short rsb[64][72];   // r * hid bf16

    const int tid  = threadIdx.x;
    const int w    = tid >> 6;
    const int lane = tid & 63;
    const int lr   = lane & 15;
    const int lg   = lane >> 4;
    const int col  = w * 16 + lr;
    const int n0   = blockIdx.x * 64;

    // ---- stage AX (bf16 direct) and hid (f32 -> bf16)
    {
        int row = tid >> 2;
        int c0  = (tid & 3) << 4;
        int n   = n0 + row;
        bool valid = n < nNodes;
        const float4 z4 = make_float4(0.f, 0.f, 0.f, 0.f);
        const bf16x8 zb = {0, 0, 0, 0, 0, 0, 0, 0};
        bf16x8 a0 = valid ? *(const bf16x8*)(AXb + (size_t)n * 64 + c0)     : zb;
        bf16x8 a1 = valid ? *(const bf16x8*)(AXb + (size_t)n * 64 + c0 + 8) : zb;
        *(bf16x8*)(&axs[row][c0])     = a0;
        *(bf16x8*)(&axs[row][c0 + 8]) = a1;
#pragma unroll
        for (int q = 0; q < 4; q++) {
            float4 vh = valid ? *(const float4*)(hid + (size_t)n * 64 + c0 + q * 4) : z4;
            int c = c0 + q * 4;
            hs[row][c + 0] = f2bf(vh.x); hs[row][c + 1] = f2bf(vh.y);
            hs[row][c + 2] = f2bf(vh.z); hs[row][c + 3] = f2bf(vh.w);
        }
    }

    // ---- B-operand fragments for all 7 matrices (56 VGPR)
    bf16x8 wf[7][2];
#pragma unroll
    for (int m = 0; m < 7; m++)
#pragma unroll
        for (int kb = 0; kb < 2; kb++)
            wf[m][kb] = *(const bf16x8*)(WT + m * 4096 + col * 64 + kb * 32 + lg * 8);
    const float bz_ = bfv[col], br_ = bfv[64 + col], bh_ = bfv[128 + col], bo_ = bfv[192 + col];

    __syncthreads();

    const f32x4 zero4 = {0.f, 0.f, 0.f, 0.f};
    f32x4 accz[4], accr[4], acch[4];
#pragma unroll
    for (int rt = 0; rt < 4; rt++) { accz[rt] = zero4; accr[rt] = zero4; acch[rt] = zero4; }

    // ---- phase A: AX-part of z,r,h and hid-part of z,r
#pragma unroll
    for (int rt = 0; rt < 4; rt++) {
        int arow = rt * 16 + lr;
#pragma unroll
        for (int kb = 0; kb < 2; kb++) {
            bf16x8 aa = *(const bf16x8*)(&axs[arow][kb * 32 + lg * 8]);
            bf16x8 ah = *(const bf16x8*)(&hs [arow][kb * 32 + lg * 8]);
            accz[rt] = __builtin_amdgcn_mfma_f32_16x16x32_bf16(aa, wf[0][kb], accz[rt], 0, 0, 0);
            accr[rt] = __builtin_amdgcn_mfma_f32_16x16x32_bf16(aa, wf[1][kb], accr[rt], 0, 0, 0);
            acch[rt] = __builtin_amdgcn_mfma_f32_16x16x32_bf16(aa, wf[2][kb], acch[rt], 0, 0, 0);
            accz[rt] = __builtin_amdgcn_mfma_f32_16x16x32_bf16(ah, wf[3][kb], accz[rt], 0, 0, 0);
            accr[rt] = __builtin_amdgcn_mfma_f32_16x16x32_bf16(ah, wf[4][kb], accr[rt], 0, 0, 0);
        }
    }

    // ---- z, r; rsb <- bf16(r * hid)
    float zf[16];
#pragma unroll
    for (int rt = 0; rt < 4; rt++) {
#pragma unroll
        for (int i = 0; i < 4; i++) {
            int row = rt * 16 + lg * 4 + i;
            float z = sigmoid_(accz[rt][i] + bz_);
            float r = sigmoid_(accr[rt][i] + br_);
            zf[rt * 4 + i] = z;
            rsb[row][col] = f2bf(r * bf2f(hs[row][col]));
        }
    }
    __syncthreads();

    // ---- phase B: h_tilde += (r*hid) @ Wlh_bot ; h ; relu(h) -> axs
#pragma unroll
    for (int rt = 0; rt < 4; rt++) {
        int arow = rt * 16 + lr;
#pragma unroll
        for (int kb = 0; kb < 2; kb++) {
            bf16x8 ar = *(const bf16x8*)(&rsb[arow][kb * 32 + lg * 8]);
            acch[rt] = __builtin_amdgcn_mfma_f32_16x16x32_bf16(ar, wf[5][kb], acch[rt], 0, 0, 0);
        }
    }
#pragma unroll
    for (int rt = 0; rt < 4; rt++) {
#pragma unroll
        for (int i = 0; i < 4; i++) {
            int row = rt * 16 + lg * 4 + i;
            float ht = tanh_(acch[rt][i] + bh_);
            float z  = zf[rt * 4 + i];
            float hv = z * bf2f(hs[row][col]) + (1.f - z) * ht;
            int n = n0 + row;
            if (n < nNodes) outH[(size_t)n * 64 + col] = hv;
            axs[row][col] = f2bf(fmaxf(hv, 0.f));
        }
    }
    __syncthreads();

    // ---- phase C: y = relu(h) @ W_out + b_out
    f32x4 accy[4];
#pragma unroll
    for (int rt = 0; rt < 4; rt++) accy[rt] = zero4;
#pragma unroll
    for (int rt = 0; rt < 4; rt++) {
        int arow = rt * 16 + lr;
#pragma unroll
        for (int kb = 0; kb < 2; kb++) {
            bf16x8 aa = *(const bf16x8*)(&axs[arow][kb * 32 + lg * 8]);
            accy[rt] = __builtin_amdgcn_mfma_f32_16x16x32_bf16(aa, wf[6][kb], accy[rt], 0, 0, 0);
        }
    }
#pragma unroll
    for (int rt = 0; rt < 4; rt++) {
#pragma unroll
        for (int i = 0; i < 4; i++) {
            int row = rt * 16 + lg * 4 + i;
            int n = n0 + row;
            if (n < nNodes) outY[(size_t)n * 64 + col] = accy[rt][i] + bo_;
        }
    }
}

extern "C" void kernel_launch(void* const* d_in, const int* in_sizes, int n_in,
                              void* d_out, int out_size, void* d_ws, size_t ws_size,
                              hipStream_t stream)
{
    const float* node_feat = (const float*)d_in[0];
    const float* edge_w    = (const float*)d_in[1];
    const float* hidden    = (const float*)d_in[2];
    const float* W_z  = (const float*)d_in[3];
    const float* b_z  = (const float*)d_in[4];
    const float* W_r  = (const float*)d_in[5];
    const float* b_r  = (const float*)d_in[6];
    const float* W_h  = (const float*)d_in[7];
    const float* b_h  = (const float*)d_in[8];
    const float* Wl_z = (const float*)d_in[9];
    const float* bl_z = (const float*)d_in[10];
    const float* Wl_r = (const float*)d_in[11];
    const float* bl_r = (const float*)d_in[12];
    const float* Wl_h = (const float*)d_in[13];
    const float* bl_h = (const float*)d_in[14];
    const float* W_out = (const float*)d_in[15];
    const float* b_out = (const float*)d_in[16];
    const int*   edge_index = (const int*)d_in[17];

    const int N = in_sizes[0] / 64;
    const int E = in_sizes[1];

    char* ws = (char*)d_ws;
    size_t off = 0;
    short* AXb = (short*)(ws + off); off += (size_t)N * 64 * 2;   // bf16 accum
    short* WT  = (short*)(ws + off); off += 7 * 4096 * 2;         // fused weights
    float* bfv = (float*)(ws + off); off += 4 * 64 * 4;           // fused biases

    float* outY = (float*)d_out;                 // [N,64]
    float* outH = outY + (size_t)N * 64;         // [N,64]

    prep_zero_kernel<<<(N * 8 + 255) / 256, 256, 0, stream>>>(AXb, N * 8);
    fuse_weights_kernel<<<4, 256, 0, stream>>>(W_z, W_r, W_h, b_z, b_r, b_h,
                                               Wl_z, Wl_r, Wl_h, bl_z, bl_r, bl_h,
                                               W_out, b_out, WT, bfv);
    scatter_kernel<<<(E * 32 + 255) / 256, 256, 0, stream>>>(
        node_feat, edge_w, edge_index, AXb, E);

    int nblk = (N + 63) / 64;
    gates_kernel<<<nblk, 256, 0, stream>>>(AXb, hidden, WT, bfv, outY, outH, N);
}